// Round 5
// baseline (469.778 us; speedup 1.0000x reference)
//
#include <hip/hip_runtime.h>
#include <math.h>

#define NN 2048
#define MM 50
#define CC 64
#define BB 64
#define EE 8192
#define NEG 0.2f
#define MARGIN_ 4.2f

// ---- probe: float sentinels, overwritten by k_out/k_loss if pipeline completes
__global__ void k_first(float* out){
  out[0] = 2048.0f;
  out[(size_t)NN*BB*CC] = 2048.0f;
}

// ---- ws-too-small sentinel (float, visible)
__global__ void k_flagout(float* out, float v){ out[0]=v; }

// ---- counts: one block per segment scans all E indices (deterministic, no atomics)
__global__ void k_counts(const int* __restrict__ nidx, const int* __restrict__ eidx,
                         int* __restrict__ ncnt, int* __restrict__ ecnt){
  __shared__ int red[256];
  int seg = blockIdx.x, t = threadIdx.x;
  int c = 0;
  if (seg < NN){
    for (int e=t;e<EE;e+=256) c += (nidx[e]==seg);
  } else {
    int m = seg-NN;
    for (int e=t;e<EE;e+=256) c += (eidx[e]==m);
  }
  red[t]=c; __syncthreads();
  for (int s=128;s>0;s>>=1){ if(t<s) red[t]+=red[t+s]; __syncthreads(); }
  if (t==0){ if (seg<NN) ncnt[seg]=red[0]; else ecnt[seg-NN]=red[0]; }
}

// ---- exclusive prefix sums (single block)
__global__ void k_offsets(const int* __restrict__ ncnt,const int* __restrict__ ecnt,
                          int* __restrict__ noff,int* __restrict__ eoff){
  __shared__ int buf[256];
  __shared__ int carry;
  int t=threadIdx.x;
  if (t==0) carry=0;
  __syncthreads();
  for (int base=0;base<NN;base+=256){
    int v = ncnt[base+t];
    buf[t]=v; __syncthreads();
    for (int o=1;o<256;o<<=1){
      int x=(t>=o)?buf[t-o]:0; __syncthreads();
      buf[t]+=x; __syncthreads();
    }
    int c = carry;
    noff[base+t] = c + buf[t]-v;
    __syncthreads();
    if (t==0) carry = c + buf[255];
    __syncthreads();
  }
  int v = (t<MM)? ecnt[t]:0;
  buf[t]=v; __syncthreads();
  for (int o=1;o<256;o<<=1){
    int x=(t>=o)?buf[t-o]:0; __syncthreads();
    buf[t]+=x; __syncthreads();
  }
  if (t<MM) eoff[t]=buf[t]-v;
}

// ---- stable CSR compaction: one wave per segment, ballot-ranked (deterministic)
__global__ void k_build(const int* __restrict__ nidx,const int* __restrict__ eidx,
                        const int* __restrict__ noff,const int* __restrict__ eoff,
                        int* __restrict__ nlist,int* __restrict__ elist){
  int seg = blockIdx.x;
  int lane = threadIdx.x;           // 64 lanes = 1 wave
  const int* key; int target, base; int* outl;
  if (seg < NN){ key=nidx; target=seg;     base=noff[seg];     outl=nlist; }
  else         { key=eidx; target=seg-NN;  base=eoff[seg-NN];  outl=elist; }
  int carry = 0;
  unsigned long long ltmask = (1ull<<lane) - 1ull;
  for (int w=0; w<EE/64; ++w){
    int e = w*64 + lane;
    bool m = (key[e]==target);
    unsigned long long bal = __ballot(m);
    if (m){
      int pos = __popcll(bal & ltmask);
      outl[base + carry + pos] = e;
    }
    carry += __popcll(bal);
  }
}

// ---- xw = x @ W staged INTO d_out (same [B,N,C] layout), + natt1/natt2 row dots
__global__ __launch_bounds__(256) void k_gemm(const float* __restrict__ x,const float* __restrict__ w,
       const float* __restrict__ att, float* __restrict__ outf,
       float* __restrict__ natt1,float* __restrict__ natt2){
  __shared__ float Wl[4096];
  __shared__ float Xl[1024];
  int t=threadIdx.x;
  for (int i=t;i<1024;i+=256) ((float4*)Wl)[i]=((const float4*)w)[i];
  size_t rbase=(size_t)blockIdx.x*16;          // 16 rows of 64
  ((float4*)Xl)[t] = ((const float4*)x)[rbase*16 + t];
  __syncthreads();
  int r=t>>4, c0=(t&15)*4;
  float4 acc=make_float4(0.f,0.f,0.f,0.f);
  #pragma unroll
  for (int k=0;k<64;++k){
    float a=Xl[r*64+k];
    float4 wv=*(const float4*)&Wl[k*64+c0];
    acc.x+=a*wv.x; acc.y+=a*wv.y; acc.z+=a*wv.z; acc.w+=a*wv.w;
  }
  int rid=(int)rbase+r;                         // rid = b*NN + n  (x is [B,N,C])
  *(float4*)&outf[(size_t)rid*CC + c0] = acc;   // xw staged in d_out, same layout
  float a1 = acc.x*att[c0]+acc.y*att[c0+1]+acc.z*att[c0+2]+acc.w*att[c0+3];
  float a2 = acc.x*att[64+c0]+acc.y*att[64+c0+1]+acc.z*att[64+c0+2]+acc.w*att[64+c0+3];
  for (int s=8;s>=1;s>>=1){ a1+=__shfl_xor(a1,s,64); a2+=__shfl_xor(a2,s,64); }
  if ((t&15)==0){
    int b=rid>>11, n=rid&2047;
    natt1[n*BB+b]=a1; natt2[n*BB+b]=a2;
  }
}

// ---- rowsum[n] = sum_{b,c} xw[n,b,c]   (xw in outf[b*N*C + n*C + c])
__global__ void k_rowsum(const float* __restrict__ outf, float* __restrict__ rowsum){
  int n=blockIdx.x, b=threadIdx.x;   // 64 lanes = 64 batches
  const float4* p=(const float4*)&outf[(size_t)b*(NN*CC) + (size_t)n*CC];
  float s=0.f;
  #pragma unroll
  for (int i=0;i<16;++i){ float4 v=p[i]; s+=v.x+v.y+v.z+v.w; }
  for (int ss=32;ss>=1;ss>>=1) s+=__shfl_xor(s,ss,64);
  if (b==0) rowsum[n]=s;
}

// ---- eatt2[m,b] = sum_{e in m} natt2[node[e],b]
__global__ void k_eatt(const int* __restrict__ elist,const int* __restrict__ eoff,
                       const int* __restrict__ ecnt,const int* __restrict__ nidx,
                       const float* __restrict__ natt2,float* __restrict__ eatt2){
  int m=blockIdx.x, b=threadIdx.x;
  int off=eoff[m], deg=ecnt[m];
  float s=0.f;
  for (int j=0;j<deg;++j){
    int e=elist[off+j]; int n=nidx[e];
    s += natt2[n*BB+b];
  }
  eatt2[m*BB+b]=s;
}

// ---- grouped softmax per node (1 wave per node, lane = batch)
__global__ void k_alpha(const int* __restrict__ nlist,const int* __restrict__ noff,
                        const int* __restrict__ ncnt,const int* __restrict__ eidx,
                        const float* __restrict__ natt1,const float* __restrict__ eatt2,
                        float* __restrict__ alpha){
  int n = blockIdx.x, b = threadIdx.x;
  int off = noff[n], deg = ncnt[n];
  if (deg==0) return;
  float na = natt1[n*BB+b];
  float mx = -1e30f;
  for (int j=0;j<deg;++j){
    int e = nlist[off+j]; int m = eidx[e];
    float l = na + eatt2[m*BB+b]; l = l>0.f? l : NEG*l;
    mx = fmaxf(mx,l);
  }
  float s=0.f;
  for (int j=0;j<deg;++j){
    int e = nlist[off+j]; int m = eidx[e];
    float l = na + eatt2[m*BB+b]; l = l>0.f? l : NEG*l;
    s += expf(l-mx);
  }
  float inv = 1.f/(s+1e-16f);
  for (int j=0;j<deg;++j){
    int e = nlist[off+j]; int m = eidx[e];
    float l = na + eatt2[m*BB+b]; l = l>0.f? l : NEG*l;
    alpha[(size_t)e*BB+b] = expf(l-mx)*inv;
  }
}

// ---- fused per-edge gather: edge_sums, edge_feat, norms (xw read from outf)
__global__ void k_edge(const int* __restrict__ elist,const int* __restrict__ eoff,
                       const int* __restrict__ ecnt,const int* __restrict__ nidx,
                       const float* __restrict__ outf,const float* __restrict__ alpha,
                       float* __restrict__ es,float* __restrict__ ef,float* __restrict__ nrm){
  int m = blockIdx.x>>2, bq = blockIdx.x&3;
  int t = threadIdx.x;
  int b = bq*16 + (t>>4);
  int c0 = (t&15)*4;
  int off = eoff[m], deg = ecnt[m];
  float4 as=make_float4(0.f,0.f,0.f,0.f), af=as;
  for (int j=0;j<deg;++j){
    int e = elist[off+j];
    int n = nidx[e];
    float al = alpha[(size_t)e*BB+b];
    float4 v = *(const float4*)&outf[(size_t)b*(NN*CC) + (size_t)n*CC + c0];
    as.x+=v.x; as.y+=v.y; as.z+=v.z; as.w+=v.w;
    af.x+=al*v.x; af.y+=al*v.y; af.z+=al*v.z; af.w+=al*v.w;
  }
  float bn = deg>0 ? 1.f/(float)deg : 0.f;
  size_t o = ((size_t)m*BB+b)*CC+c0;
  *(float4*)&es[o]=as;
  float4 f; f.x=af.x*bn; f.y=af.y*bn; f.z=af.z*bn; f.w=af.w*bn;
  *(float4*)&ef[o]=f;
  float ssq = as.x*as.x+as.y*as.y+as.z*as.z+as.w*as.w;
  for (int s=8;s>=1;s>>=1) ssq += __shfl_xor(ssq,s,64);
  if ((t&15)==0) nrm[m*BB+b] = ssq>0.f? sqrtf(ssq):0.f;
}

// ---- pairwise hyperedge loss, one block per (k,m), lane = batch
__global__ void k_pair(const float* __restrict__ es,const float* __restrict__ nrm,
                       float* __restrict__ pairl){
  int kk = blockIdx.x / MM, m = blockIdx.x % MM;
  int b = threadIdx.x;
  const float4* pa = (const float4*)&es[((size_t)kk*BB+b)*CC];
  const float4* pb = (const float4*)&es[((size_t)m*BB+b)*CC];
  float inner=0.f, d2=0.f;
  #pragma unroll
  for (int q=0;q<16;++q){
    float4 a=pa[q], c=pb[q];
    inner += a.x*c.x+a.y*c.y+a.z*c.z+a.w*c.w;
    float dx=a.x-c.x, dy=a.y-c.y, dz=a.z-c.z, dw=a.w-c.w;
    d2 += dx*dx+dy*dy+dz*dz+dw*dw;
  }
  float dist = d2>0.f? sqrtf(d2):0.f;
  float cosv = inner/(nrm[kk*BB+b]*nrm[m*BB+b]);
  float li = cosv*dist + (1.f-cosv)*fmaxf(MARGIN_-dist,0.f);
  for (int s=32;s>=1;s>>=1) li += __shfl_xor(li,s,64);
  if (b==0) pairl[blockIdx.x] = fabsf(li*(1.f/64.f));
}

// ---- out[b,n,c] = D[n] * sum_{e in n} alpha[e,b]*ef[edge[e],b,c]; overwrites xw stage
__global__ void k_out(const int* __restrict__ nlist,const int* __restrict__ noff,
                      const int* __restrict__ ncnt,const int* __restrict__ eidx,
                      const float* __restrict__ alpha,const float* __restrict__ ef,
                      float* __restrict__ outf){
  int n = blockIdx.x, t = threadIdx.x;
  int b = t>>2, sub = t&3;           // 16 floats per thread
  int off = noff[n], deg = ncnt[n];
  float4 a0=make_float4(0.f,0.f,0.f,0.f),a1=a0,a2=a0,a3=a0;
  for (int j=0;j<deg;++j){
    int e = nlist[off+j]; int m = eidx[e];
    float al = alpha[(size_t)e*BB+b];
    const float4* p = (const float4*)&ef[((size_t)m*BB+b)*CC + sub*16];
    float4 v0=p[0],v1=p[1],v2=p[2],v3=p[3];
    a0.x+=al*v0.x; a0.y+=al*v0.y; a0.z+=al*v0.z; a0.w+=al*v0.w;
    a1.x+=al*v1.x; a1.y+=al*v1.y; a1.z+=al*v1.z; a1.w+=al*v1.w;
    a2.x+=al*v2.x; a2.y+=al*v2.y; a2.z+=al*v2.z; a2.w+=al*v2.w;
    a3.x+=al*v3.x; a3.y+=al*v3.y; a3.z+=al*v3.z; a3.w+=al*v3.w;
  }
  float D=(float)deg;
  float* o = &outf[(size_t)b*(NN*CC) + (size_t)n*CC + sub*16];
  float4 w0=make_float4(D*a0.x,D*a0.y,D*a0.z,D*a0.w);
  float4 w1=make_float4(D*a1.x,D*a1.y,D*a1.z,D*a1.w);
  float4 w2=make_float4(D*a2.x,D*a2.y,D*a2.z,D*a2.w);
  float4 w3=make_float4(D*a3.x,D*a3.y,D*a3.z,D*a3.w);
  ((float4*)o)[0]=w0; ((float4*)o)[1]=w1; ((float4*)o)[2]=w2; ((float4*)o)[3]=w3;
}

// ---- final scalar: loss_hyper + |mean(x_i - x_j)|  (float write)
__global__ void k_loss(const float* __restrict__ pairl,const float* __restrict__ rowsum,
                       const int* __restrict__ ncnt,const float* __restrict__ es,
                       const int* __restrict__ ecnt, float* __restrict__ out){
  __shared__ float r1[256],r2[256],r3[256];
  int t=threadIdx.x;
  float s1=0.f,s2=0.f,s3=0.f;
  for (int i=t;i<MM*MM;i+=256) s1+=pairl[i];
  for (int i=t;i<NN;i+=256) s2+=rowsum[i]*(float)ncnt[i];
  for (int i=t;i<MM*BB*CC;i+=256) s3+=es[i]*(float)ecnt[i>>12];
  r1[t]=s1;r2[t]=s2;r3[t]=s3; __syncthreads();
  for (int s=128;s>0;s>>=1){ if(t<s){r1[t]+=r1[t+s];r2[t]+=r2[t+s];r3[t]+=r3[t+s];} __syncthreads(); }
  if (t==0){
    float lh = r1[0]/2601.f;                           // /(M+1)^2
    float con = fabsf((r2[0]-r3[0])*(1.f/33554432.f)); // /(E*B*C)
    out[(size_t)NN*BB*CC] = con+lh;
  }
}

extern "C" void kernel_launch(void* const* d_in, const int* in_sizes, int n_in,
                              void* d_out, int out_size, void* d_ws, size_t ws_size,
                              hipStream_t stream){
  (void)in_sizes; (void)n_in; (void)out_size;
  const float* x    = (const float*)d_in[0];
  const float* w    = (const float*)d_in[1];
  const float* att  = (const float*)d_in[2];
  const int*   nidx = (const int*)d_in[3];
  const int*   eidx = (const int*)d_in[4];
  float* outf = (float*)d_out;                    // reference outputs are float32

  char* ws = (char*)d_ws;
  size_t off = 0;
  auto alloc = [&](size_t bytes)->void*{ void* p = ws + off; off = (off + bytes + 255) & ~(size_t)255; return p; };
  float* natt1 = (float*)alloc(sizeof(float)*NN*BB);
  float* natt2 = (float*)alloc(sizeof(float)*NN*BB);
  float* eatt2 = (float*)alloc(sizeof(float)*MM*BB);
  float* alpha = (float*)alloc(sizeof(float)*(size_t)EE*BB);
  float* es    = (float*)alloc(sizeof(float)*MM*BB*CC);
  float* ef    = (float*)alloc(sizeof(float)*MM*BB*CC);
  float* nrm   = (float*)alloc(sizeof(float)*MM*BB);
  float* pairl = (float*)alloc(sizeof(float)*MM*MM);
  float* rowsum= (float*)alloc(sizeof(float)*NN);
  int* ncnt = (int*)alloc(sizeof(int)*NN);
  int* noff = (int*)alloc(sizeof(int)*NN);
  int* ecnt = (int*)alloc(sizeof(int)*MM);
  int* eoff = (int*)alloc(sizeof(int)*MM);
  int* nlist= (int*)alloc(sizeof(int)*EE);
  int* elist= (int*)alloc(sizeof(int)*EE);
  // total ~4.4 MB

  if (ws_size < off){ // workspace insufficient: float sentinel 16384
    k_flagout<<<1,1,0,stream>>>(outf, 16384.f);
    return;
  }

  k_first  <<<1, 1, 0, stream>>>(outf);
  k_counts <<<NN+MM, 256, 0, stream>>>(nidx, eidx, ncnt, ecnt);
  k_offsets<<<1, 256, 0, stream>>>(ncnt, ecnt, noff, eoff);
  k_build  <<<NN+MM, 64, 0, stream>>>(nidx, eidx, noff, eoff, nlist, elist);
  k_gemm   <<<(NN*BB)/16, 256, 0, stream>>>(x, w, att, outf, natt1, natt2);
  k_rowsum <<<NN, 64, 0, stream>>>(outf, rowsum);
  k_eatt   <<<MM, 64, 0, stream>>>(elist, eoff, ecnt, nidx, natt2, eatt2);
  k_alpha  <<<NN, 64, 0, stream>>>(nlist, noff, ncnt, eidx, natt1, eatt2, alpha);
  k_edge   <<<MM*4, 256, 0, stream>>>(elist, eoff, ecnt, nidx, outf, alpha, es, ef, nrm);
  k_pair   <<<MM*MM, 64, 0, stream>>>(es, nrm, pairl);
  k_out    <<<NN, 256, 0, stream>>>(nlist, noff, ncnt, eidx, alpha, ef, outf);
  k_loss   <<<1, 256, 0, stream>>>(pairl, rowsum, ncnt, es, ecnt, outf);
}

// Round 6
// 270.485 us; speedup vs baseline: 1.7368x; 1.7368x over previous
//
#include <hip/hip_runtime.h>
#include <math.h>

#define NN 2048
#define MM 50
#define CC 64
#define BB 64
#define EE 8192
#define NEG 0.2f
#define MARGIN_ 4.2f

// ---- counts: one block per segment scans all E indices (deterministic, no atomics)
__global__ void k_counts(const int* __restrict__ nidx, const int* __restrict__ eidx,
                         int* __restrict__ ncnt, int* __restrict__ ecnt){
  __shared__ int red[256];
  int seg = blockIdx.x, t = threadIdx.x;
  int c = 0;
  if (seg < NN){
    for (int e=t;e<EE;e+=256) c += (nidx[e]==seg);
  } else {
    int m = seg-NN;
    for (int e=t;e<EE;e+=256) c += (eidx[e]==m);
  }
  red[t]=c; __syncthreads();
  for (int s=128;s>0;s>>=1){ if(t<s) red[t]+=red[t+s]; __syncthreads(); }
  if (t==0){ if (seg<NN) ncnt[seg]=red[0]; else ecnt[seg-NN]=red[0]; }
}

// ---- exclusive prefix sums (single block)
__global__ void k_offsets(const int* __restrict__ ncnt,const int* __restrict__ ecnt,
                          int* __restrict__ noff,int* __restrict__ eoff){
  __shared__ int buf[256];
  __shared__ int carry;
  int t=threadIdx.x;
  if (t==0) carry=0;
  __syncthreads();
  for (int base=0;base<NN;base+=256){
    int v = ncnt[base+t];
    buf[t]=v; __syncthreads();
    for (int o=1;o<256;o<<=1){
      int x=(t>=o)?buf[t-o]:0; __syncthreads();
      buf[t]+=x; __syncthreads();
    }
    int c = carry;
    noff[base+t] = c + buf[t]-v;
    __syncthreads();
    if (t==0) carry = c + buf[255];
    __syncthreads();
  }
  int v = (t<MM)? ecnt[t]:0;
  buf[t]=v; __syncthreads();
  for (int o=1;o<256;o<<=1){
    int x=(t>=o)?buf[t-o]:0; __syncthreads();
    buf[t]+=x; __syncthreads();
  }
  if (t<MM) eoff[t]=buf[t]-v;
}

// ---- stable CSR compaction: one wave per segment, ballot-ranked (deterministic)
__global__ void k_build(const int* __restrict__ nidx,const int* __restrict__ eidx,
                        const int* __restrict__ noff,const int* __restrict__ eoff,
                        int* __restrict__ nlist,int* __restrict__ elist){
  int seg = blockIdx.x;
  int lane = threadIdx.x;           // 64 lanes = 1 wave
  const int* key; int target, base; int* outl;
  if (seg < NN){ key=nidx; target=seg;     base=noff[seg];     outl=nlist; }
  else         { key=eidx; target=seg-NN;  base=eoff[seg-NN];  outl=elist; }
  int carry = 0;
  unsigned long long ltmask = (1ull<<lane) - 1ull;
  for (int w=0; w<EE/64; ++w){
    int e = w*64 + lane;
    bool m = (key[e]==target);
    unsigned long long bal = __ballot(m);
    if (m){
      int pos = __popcll(bal & ltmask);
      outl[base + carry + pos] = e;
    }
    carry += __popcll(bal);
  }
}

// ---- xw = x @ W staged INTO d_out (same [B,N,C] layout), + natt1/natt2 row dots
__global__ __launch_bounds__(256) void k_gemm(const float* __restrict__ x,const float* __restrict__ w,
       const float* __restrict__ att, float* __restrict__ outf,
       float* __restrict__ natt1,float* __restrict__ natt2){
  __shared__ float Wl[4096];
  __shared__ float Xl[1024];
  int t=threadIdx.x;
  for (int i=t;i<1024;i+=256) ((float4*)Wl)[i]=((const float4*)w)[i];
  size_t rbase=(size_t)blockIdx.x*16;          // 16 rows of 64
  ((float4*)Xl)[t] = ((const float4*)x)[rbase*16 + t];
  __syncthreads();
  int r=t>>4, c0=(t&15)*4;
  float4 acc=make_float4(0.f,0.f,0.f,0.f);
  #pragma unroll
  for (int k=0;k<64;++k){
    float a=Xl[r*64+k];
    float4 wv=*(const float4*)&Wl[k*64+c0];
    acc.x+=a*wv.x; acc.y+=a*wv.y; acc.z+=a*wv.z; acc.w+=a*wv.w;
  }
  int rid=(int)rbase+r;                         // rid = b*NN + n  (x is [B,N,C])
  *(float4*)&outf[(size_t)rid*CC + c0] = acc;   // xw staged in d_out, same layout
  float a1 = acc.x*att[c0]+acc.y*att[c0+1]+acc.z*att[c0+2]+acc.w*att[c0+3];
  float a2 = acc.x*att[64+c0]+acc.y*att[64+c0+1]+acc.z*att[64+c0+2]+acc.w*att[64+c0+3];
  for (int s=8;s>=1;s>>=1){ a1+=__shfl_xor(a1,s,64); a2+=__shfl_xor(a2,s,64); }
  if ((t&15)==0){
    int b=rid>>11, n=rid&2047;
    natt1[n*BB+b]=a1; natt2[n*BB+b]=a2;
  }
}

// ---- rowsum[n] = sum_{b,c} xw[n,b,c]   (xw in outf[b*N*C + n*C + c])
__global__ void k_rowsum(const float* __restrict__ outf, float* __restrict__ rowsum){
  int n=blockIdx.x, b=threadIdx.x;   // 64 lanes = 64 batches
  const float4* p=(const float4*)&outf[(size_t)b*(NN*CC) + (size_t)n*CC];
  float s=0.f;
  #pragma unroll
  for (int i=0;i<16;++i){ float4 v=p[i]; s+=v.x+v.y+v.z+v.w; }
  for (int ss=32;ss>=1;ss>>=1) s+=__shfl_xor(s,ss,64);
  if (b==0) rowsum[n]=s;
}

// ---- eatt2[m,b] = sum_{e in m} natt2[node[e],b]
__global__ void k_eatt(const int* __restrict__ elist,const int* __restrict__ eoff,
                       const int* __restrict__ ecnt,const int* __restrict__ nidx,
                       const float* __restrict__ natt2,float* __restrict__ eatt2){
  int m=blockIdx.x, b=threadIdx.x;
  int off=eoff[m], deg=ecnt[m];
  float s=0.f;
  for (int j=0;j<deg;++j){
    int e=elist[off+j]; int n=nidx[e];
    s += natt2[n*BB+b];
  }
  eatt2[m*BB+b]=s;
}

// ---- grouped softmax per node (1 wave per node, lane = batch)
__global__ void k_alpha(const int* __restrict__ nlist,const int* __restrict__ noff,
                        const int* __restrict__ ncnt,const int* __restrict__ eidx,
                        const float* __restrict__ natt1,const float* __restrict__ eatt2,
                        float* __restrict__ alpha){
  int n = blockIdx.x, b = threadIdx.x;
  int off = noff[n], deg = ncnt[n];
  if (deg==0) return;
  float na = natt1[n*BB+b];
  float mx = -1e30f;
  for (int j=0;j<deg;++j){
    int e = nlist[off+j]; int m = eidx[e];
    float l = na + eatt2[m*BB+b]; l = l>0.f? l : NEG*l;
    mx = fmaxf(mx,l);
  }
  float s=0.f;
  for (int j=0;j<deg;++j){
    int e = nlist[off+j]; int m = eidx[e];
    float l = na + eatt2[m*BB+b]; l = l>0.f? l : NEG*l;
    s += expf(l-mx);
  }
  float inv = 1.f/(s+1e-16f);
  for (int j=0;j<deg;++j){
    int e = nlist[off+j]; int m = eidx[e];
    float l = na + eatt2[m*BB+b]; l = l>0.f? l : NEG*l;
    alpha[(size_t)e*BB+b] = expf(l-mx)*inv;
  }
}

// ---- fused per-edge gather: edge_sums, edge_feat, norms (xw read from outf)
__global__ void k_edge(const int* __restrict__ elist,const int* __restrict__ eoff,
                       const int* __restrict__ ecnt,const int* __restrict__ nidx,
                       const float* __restrict__ outf,const float* __restrict__ alpha,
                       float* __restrict__ es,float* __restrict__ ef,float* __restrict__ nrm){
  int m = blockIdx.x>>2, bq = blockIdx.x&3;
  int t = threadIdx.x;
  int b = bq*16 + (t>>4);
  int c0 = (t&15)*4;
  int off = eoff[m], deg = ecnt[m];
  float4 as=make_float4(0.f,0.f,0.f,0.f), af=as;
  for (int j=0;j<deg;++j){
    int e = elist[off+j];
    int n = nidx[e];
    float al = alpha[(size_t)e*BB+b];
    float4 v = *(const float4*)&outf[(size_t)b*(NN*CC) + (size_t)n*CC + c0];
    as.x+=v.x; as.y+=v.y; as.z+=v.z; as.w+=v.w;
    af.x+=al*v.x; af.y+=al*v.y; af.z+=al*v.z; af.w+=al*v.w;
  }
  float bn = deg>0 ? 1.f/(float)deg : 0.f;
  size_t o = ((size_t)m*BB+b)*CC+c0;
  *(float4*)&es[o]=as;
  float4 f; f.x=af.x*bn; f.y=af.y*bn; f.z=af.z*bn; f.w=af.w*bn;
  *(float4*)&ef[o]=f;
  float ssq = as.x*as.x+as.y*as.y+as.z*as.z+as.w*as.w;
  for (int s=8;s>=1;s>>=1) ssq += __shfl_xor(ssq,s,64);
  if ((t&15)==0) nrm[m*BB+b] = ssq>0.f? sqrtf(ssq):0.f;
}

// ---- pairwise hyperedge loss, one block per (k,m), lane = batch
__global__ void k_pair(const float* __restrict__ es,const float* __restrict__ nrm,
                       float* __restrict__ pairl){
  int kk = blockIdx.x / MM, m = blockIdx.x % MM;
  int b = threadIdx.x;
  const float4* pa = (const float4*)&es[((size_t)kk*BB+b)*CC];
  const float4* pb = (const float4*)&es[((size_t)m*BB+b)*CC];
  float inner=0.f, d2=0.f;
  #pragma unroll
  for (int q=0;q<16;++q){
    float4 a=pa[q], c=pb[q];
    inner += a.x*c.x+a.y*c.y+a.z*c.z+a.w*c.w;
    float dx=a.x-c.x, dy=a.y-c.y, dz=a.z-c.z, dw=a.w-c.w;
    d2 += dx*dx+dy*dy+dz*dz+dw*dw;
  }
  float dist = d2>0.f? sqrtf(d2):0.f;
  float cosv = inner/(nrm[kk*BB+b]*nrm[m*BB+b]);
  float li = cosv*dist + (1.f-cosv)*fmaxf(MARGIN_-dist,0.f);
  for (int s=32;s>=1;s>>=1) li += __shfl_xor(li,s,64);
  if (b==0) pairl[blockIdx.x] = fabsf(li*(1.f/64.f));
}

// ---- out[b,n,c] = D[n] * sum_{e in n} alpha[e,b]*ef[edge[e],b,c]; overwrites xw stage
__global__ void k_out(const int* __restrict__ nlist,const int* __restrict__ noff,
                      const int* __restrict__ ncnt,const int* __restrict__ eidx,
                      const float* __restrict__ alpha,const float* __restrict__ ef,
                      float* __restrict__ outf){
  int n = blockIdx.x, t = threadIdx.x;
  int b = t>>2, sub = t&3;           // 16 floats per thread
  int off = noff[n], deg = ncnt[n];
  float4 a0=make_float4(0.f,0.f,0.f,0.f),a1=a0,a2=a0,a3=a0;
  for (int j=0;j<deg;++j){
    int e = nlist[off+j]; int m = eidx[e];
    float al = alpha[(size_t)e*BB+b];
    const float4* p = (const float4*)&ef[((size_t)m*BB+b)*CC + sub*16];
    float4 v0=p[0],v1=p[1],v2=p[2],v3=p[3];
    a0.x+=al*v0.x; a0.y+=al*v0.y; a0.z+=al*v0.z; a0.w+=al*v0.w;
    a1.x+=al*v1.x; a1.y+=al*v1.y; a1.z+=al*v1.z; a1.w+=al*v1.w;
    a2.x+=al*v2.x; a2.y+=al*v2.y; a2.z+=al*v2.z; a2.w+=al*v2.w;
    a3.x+=al*v3.x; a3.y+=al*v3.y; a3.z+=al*v3.z; a3.w+=al*v3.w;
  }
  float D=(float)deg;
  float* o = &outf[(size_t)b*(NN*CC) + (size_t)n*CC + sub*16];
  float4 w0=make_float4(D*a0.x,D*a0.y,D*a0.z,D*a0.w);
  float4 w1=make_float4(D*a1.x,D*a1.y,D*a1.z,D*a1.w);
  float4 w2=make_float4(D*a2.x,D*a2.y,D*a2.z,D*a2.w);
  float4 w3=make_float4(D*a3.x,D*a3.y,D*a3.z,D*a3.w);
  ((float4*)o)[0]=w0; ((float4*)o)[1]=w1; ((float4*)o)[2]=w2; ((float4*)o)[3]=w3;
}

// ---- loss reduction stage 1: 256 blocks, fixed strided partition (deterministic)
__global__ __launch_bounds__(256) void k_lred(const float* __restrict__ pairl,
                       const float* __restrict__ rowsum,const int* __restrict__ ncnt,
                       const float* __restrict__ es,const int* __restrict__ ecnt,
                       float* __restrict__ partial){
  __shared__ float r1[256],r2[256],r3[256];
  int t=threadIdx.x;
  int gid = blockIdx.x*256+t, stride = 256*256;
  float s1=0.f,s2=0.f,s3=0.f;
  for (int i=gid;i<MM*MM;i+=stride)    s1+=pairl[i];
  for (int i=gid;i<NN;i+=stride)       s2+=rowsum[i]*(float)ncnt[i];
  for (int i=gid;i<MM*BB*CC;i+=stride) s3+=es[i]*(float)ecnt[i>>12];
  r1[t]=s1;r2[t]=s2;r3[t]=s3; __syncthreads();
  for (int s=128;s>0;s>>=1){ if(t<s){r1[t]+=r1[t+s];r2[t]+=r2[t+s];r3[t]+=r3[t+s];} __syncthreads(); }
  if (t==0){
    partial[blockIdx.x*3+0]=r1[0];
    partial[blockIdx.x*3+1]=r2[0];
    partial[blockIdx.x*3+2]=r3[0];
  }
}

// ---- loss reduction stage 2: one block over 256 partials
__global__ void k_lfin(const float* __restrict__ partial, float* __restrict__ out){
  __shared__ float r1[256],r2[256],r3[256];
  int t=threadIdx.x;
  r1[t]=partial[t*3+0]; r2[t]=partial[t*3+1]; r3[t]=partial[t*3+2];
  __syncthreads();
  for (int s=128;s>0;s>>=1){ if(t<s){r1[t]+=r1[t+s];r2[t]+=r2[t+s];r3[t]+=r3[t+s];} __syncthreads(); }
  if (t==0){
    float lh = r1[0]/2601.f;                           // /(M+1)^2
    float con = fabsf((r2[0]-r3[0])*(1.f/33554432.f)); // /(E*B*C)
    out[(size_t)NN*BB*CC] = con+lh;
  }
}

extern "C" void kernel_launch(void* const* d_in, const int* in_sizes, int n_in,
                              void* d_out, int out_size, void* d_ws, size_t ws_size,
                              hipStream_t stream){
  (void)in_sizes; (void)n_in; (void)out_size; (void)ws_size;
  const float* x    = (const float*)d_in[0];
  const float* w    = (const float*)d_in[1];
  const float* att  = (const float*)d_in[2];
  const int*   nidx = (const int*)d_in[3];
  const int*   eidx = (const int*)d_in[4];
  float* outf = (float*)d_out;                    // reference outputs are float32

  char* ws = (char*)d_ws;
  size_t off = 0;
  auto alloc = [&](size_t bytes)->void*{ void* p = ws + off; off = (off + bytes + 255) & ~(size_t)255; return p; };
  float* natt1 = (float*)alloc(sizeof(float)*NN*BB);
  float* natt2 = (float*)alloc(sizeof(float)*NN*BB);
  float* eatt2 = (float*)alloc(sizeof(float)*MM*BB);
  float* alpha = (float*)alloc(sizeof(float)*(size_t)EE*BB);
  float* es    = (float*)alloc(sizeof(float)*MM*BB*CC);
  float* ef    = (float*)alloc(sizeof(float)*MM*BB*CC);
  float* nrm   = (float*)alloc(sizeof(float)*MM*BB);
  float* pairl = (float*)alloc(sizeof(float)*MM*MM);
  float* rowsum= (float*)alloc(sizeof(float)*NN);
  float* partial=(float*)alloc(sizeof(float)*256*3);
  int* ncnt = (int*)alloc(sizeof(int)*NN);
  int* noff = (int*)alloc(sizeof(int)*NN);
  int* ecnt = (int*)alloc(sizeof(int)*MM);
  int* eoff = (int*)alloc(sizeof(int)*MM);
  int* nlist= (int*)alloc(sizeof(int)*EE);
  int* elist= (int*)alloc(sizeof(int)*EE);
  // total ~4.4 MB

  k_counts <<<NN+MM, 256, 0, stream>>>(nidx, eidx, ncnt, ecnt);
  k_offsets<<<1, 256, 0, stream>>>(ncnt, ecnt, noff, eoff);
  k_build  <<<NN+MM, 64, 0, stream>>>(nidx, eidx, noff, eoff, nlist, elist);
  k_gemm   <<<(NN*BB)/16, 256, 0, stream>>>(x, w, att, outf, natt1, natt2);
  k_rowsum <<<NN, 64, 0, stream>>>(outf, rowsum);
  k_eatt   <<<MM, 64, 0, stream>>>(elist, eoff, ecnt, nidx, natt2, eatt2);
  k_alpha  <<<NN, 64, 0, stream>>>(nlist, noff, ncnt, eidx, natt1, eatt2, alpha);
  k_edge   <<<MM*4, 256, 0, stream>>>(elist, eoff, ecnt, nidx, outf, alpha, es, ef, nrm);
  k_pair   <<<MM*MM, 64, 0, stream>>>(es, nrm, pairl);
  k_out    <<<NN, 256, 0, stream>>>(nlist, noff, ncnt, eidx, alpha, ef, outf);
  k_lred   <<<256, 256, 0, stream>>>(pairl, rowsum, ncnt, es, ecnt, partial);
  k_lfin   <<<1, 256, 0, stream>>>(partial, outf);
}

// Round 7
// 175.492 us; speedup vs baseline: 2.6769x; 1.5413x over previous
//
#include <hip/hip_runtime.h>
#include <math.h>

#define NN 2048
#define MM 50
#define CC 64
#define BB 64
#define EE 8192
#define NEG 0.2f
#define MARGIN_ 4.2f
#define ETILE 320   // max incidences staged per tile (max deg ~210 for E/M=164)

// ---- counts: one block per segment scans all E indices (deterministic, no atomics)
__global__ void k_counts(const int* __restrict__ nidx, const int* __restrict__ eidx,
                         int* __restrict__ ncnt, int* __restrict__ ecnt){
  __shared__ int red[256];
  int seg = blockIdx.x, t = threadIdx.x;
  int c = 0;
  if (seg < NN){
    for (int e=t;e<EE;e+=256) c += (nidx[e]==seg);
  } else {
    int m = seg-NN;
    for (int e=t;e<EE;e+=256) c += (eidx[e]==m);
  }
  red[t]=c; __syncthreads();
  for (int s=128;s>0;s>>=1){ if(t<s) red[t]+=red[t+s]; __syncthreads(); }
  if (t==0){ if (seg<NN) ncnt[seg]=red[0]; else ecnt[seg-NN]=red[0]; }
}

// ---- exclusive prefix sums (single block)
__global__ void k_offsets(const int* __restrict__ ncnt,const int* __restrict__ ecnt,
                          int* __restrict__ noff,int* __restrict__ eoff){
  __shared__ int buf[256];
  __shared__ int carry;
  int t=threadIdx.x;
  if (t==0) carry=0;
  __syncthreads();
  for (int base=0;base<NN;base+=256){
    int v = ncnt[base+t];
    buf[t]=v; __syncthreads();
    for (int o=1;o<256;o<<=1){
      int x=(t>=o)?buf[t-o]:0; __syncthreads();
      buf[t]+=x; __syncthreads();
    }
    int c = carry;
    noff[base+t] = c + buf[t]-v;
    __syncthreads();
    if (t==0) carry = c + buf[255];
    __syncthreads();
  }
  int v = (t<MM)? ecnt[t]:0;
  buf[t]=v; __syncthreads();
  for (int o=1;o<256;o<<=1){
    int x=(t>=o)?buf[t-o]:0; __syncthreads();
    buf[t]+=x; __syncthreads();
  }
  if (t<MM) eoff[t]=buf[t]-v;
}

// ---- stable CSR compaction: one wave per segment, ballot-ranked (deterministic)
__global__ void k_build(const int* __restrict__ nidx,const int* __restrict__ eidx,
                        const int* __restrict__ noff,const int* __restrict__ eoff,
                        int* __restrict__ nlist,int* __restrict__ elist){
  int seg = blockIdx.x;
  int lane = threadIdx.x;           // 64 lanes = 1 wave
  const int* key; int target, base; int* outl;
  if (seg < NN){ key=nidx; target=seg;     base=noff[seg];     outl=nlist; }
  else         { key=eidx; target=seg-NN;  base=eoff[seg-NN];  outl=elist; }
  int carry = 0;
  unsigned long long ltmask = (1ull<<lane) - 1ull;
  for (int w=0; w<EE/64; ++w){
    int e = w*64 + lane;
    bool m = (key[e]==target);
    unsigned long long bal = __ballot(m);
    if (m){
      int pos = __popcll(bal & ltmask);
      outl[base + carry + pos] = e;
    }
    carry += __popcll(bal);
  }
}

// ---- xw = x @ W staged INTO d_out (same [B,N,C] layout), + natt1/natt2 row dots
__global__ __launch_bounds__(256) void k_gemm(const float* __restrict__ x,const float* __restrict__ w,
       const float* __restrict__ att, float* __restrict__ outf,
       float* __restrict__ natt1,float* __restrict__ natt2){
  __shared__ float Wl[4096];
  __shared__ float Xl[1024];
  int t=threadIdx.x;
  for (int i=t;i<1024;i+=256) ((float4*)Wl)[i]=((const float4*)w)[i];
  size_t rbase=(size_t)blockIdx.x*16;          // 16 rows of 64
  ((float4*)Xl)[t] = ((const float4*)x)[rbase*16 + t];
  __syncthreads();
  int r=t>>4, c0=(t&15)*4;
  float4 acc=make_float4(0.f,0.f,0.f,0.f);
  #pragma unroll
  for (int k=0;k<64;++k){
    float a=Xl[r*64+k];
    float4 wv=*(const float4*)&Wl[k*64+c0];
    acc.x+=a*wv.x; acc.y+=a*wv.y; acc.z+=a*wv.z; acc.w+=a*wv.w;
  }
  int rid=(int)rbase+r;                         // rid = b*NN + n  (x is [B,N,C])
  *(float4*)&outf[(size_t)rid*CC + c0] = acc;   // xw staged in d_out, same layout
  float a1 = acc.x*att[c0]+acc.y*att[c0+1]+acc.z*att[c0+2]+acc.w*att[c0+3];
  float a2 = acc.x*att[64+c0]+acc.y*att[64+c0+1]+acc.z*att[64+c0+2]+acc.w*att[64+c0+3];
  for (int s=8;s>=1;s>>=1){ a1+=__shfl_xor(a1,s,64); a2+=__shfl_xor(a2,s,64); }
  if ((t&15)==0){
    int b=rid>>11, n=rid&2047;
    natt1[n*BB+b]=a1; natt2[n*BB+b]=a2;
  }
}

// ---- rowsum[n] = sum_{b,c} xw[n,b,c]   (xw in outf[b*N*C + n*C + c])
__global__ void k_rowsum(const float* __restrict__ outf, float* __restrict__ rowsum){
  int n=blockIdx.x, b=threadIdx.x;   // 64 lanes = 64 batches
  const float4* p=(const float4*)&outf[(size_t)b*(NN*CC) + (size_t)n*CC];
  float s=0.f;
  #pragma unroll
  for (int i=0;i<16;++i){ float4 v=p[i]; s+=v.x+v.y+v.z+v.w; }
  for (int ss=32;ss>=1;ss>>=1) s+=__shfl_xor(s,ss,64);
  if (b==0) rowsum[n]=s;
}

// ---- eatt2[m,b] = sum_{e in m} natt2[node[e],b]  -- LDS-staged, 4-chunk ILP
__global__ __launch_bounds__(256) void k_eatt(const int* __restrict__ elist,const int* __restrict__ eoff,
                       const int* __restrict__ ecnt,const int* __restrict__ nidx,
                       const float* __restrict__ natt2,float* __restrict__ eatt2){
  __shared__ int lds_n[ETILE];
  __shared__ float part[256];
  int m=blockIdx.x, t=threadIdx.x;
  int b = t&63, ck = t>>6;                 // 4 chunks
  int off=eoff[m], deg=ecnt[m];
  float s=0.f;
  for (int tb=0; tb<deg; tb+=ETILE){
    int tl = min(ETILE, deg-tb);
    __syncthreads();
    for (int j=t;j<tl;j+=256) lds_n[j]=nidx[elist[off+tb+j]];
    __syncthreads();
    int j0=(tl*ck)>>2, j1=(tl*(ck+1))>>2;
    for (int j=j0;j<j1;++j) s += natt2[lds_n[j]*BB+b];
  }
  part[t]=s; __syncthreads();
  if (t<64) eatt2[m*BB+b] = (part[b]+part[64+b])+(part[128+b]+part[192+b]);
}

// ---- grouped softmax per node (1 wave per node, lane = batch)
__global__ void k_alpha(const int* __restrict__ nlist,const int* __restrict__ noff,
                        const int* __restrict__ ncnt,const int* __restrict__ eidx,
                        const float* __restrict__ natt1,const float* __restrict__ eatt2,
                        float* __restrict__ alpha){
  int n = blockIdx.x, b = threadIdx.x;
  int off = noff[n], deg = ncnt[n];
  if (deg==0) return;
  float na = natt1[n*BB+b];
  float mx = -1e30f;
  for (int j=0;j<deg;++j){
    int e = nlist[off+j]; int m = eidx[e];
    float l = na + eatt2[m*BB+b]; l = l>0.f? l : NEG*l;
    mx = fmaxf(mx,l);
  }
  float s=0.f;
  for (int j=0;j<deg;++j){
    int e = nlist[off+j]; int m = eidx[e];
    float l = na + eatt2[m*BB+b]; l = l>0.f? l : NEG*l;
    s += expf(l-mx);
  }
  float inv = 1.f/(s+1e-16f);
  for (int j=0;j<deg;++j){
    int e = nlist[off+j]; int m = eidx[e];
    float l = na + eatt2[m*BB+b]; l = l>0.f? l : NEG*l;
    alpha[(size_t)e*BB+b] = expf(l-mx)*inv;
  }
}

// ---- fused per-edge gather: edge_sums, edge_feat, norms -- LDS index/alpha staging
__global__ __launch_bounds__(256) void k_edge(const int* __restrict__ elist,const int* __restrict__ eoff,
                       const int* __restrict__ ecnt,const int* __restrict__ nidx,
                       const float* __restrict__ outf,const float* __restrict__ alpha,
                       float* __restrict__ es,float* __restrict__ ef,float* __restrict__ nrm){
  __shared__ int   lds_e[ETILE];
  __shared__ int   lds_n[ETILE];
  __shared__ float lds_al[ETILE*16];
  int m = blockIdx.x>>2, bq = blockIdx.x&3;
  int t = threadIdx.x;
  int bi = t>>4;                 // 0..15
  int b  = bq*16 + bi;
  int c0 = (t&15)*4;
  int off = eoff[m], deg = ecnt[m];
  float4 as=make_float4(0.f,0.f,0.f,0.f), af=as;
  for (int tb=0; tb<deg; tb+=ETILE){
    int tl = min(ETILE, deg-tb);
    __syncthreads();                               // previous tile fully consumed
    for (int j=t;j<tl;j+=256){
      int e = elist[off+tb+j];
      lds_e[j]=e; lds_n[j]=nidx[e];
    }
    __syncthreads();
    for (int idx=t; idx<tl*16; idx+=256){
      int j=idx>>4, b2=idx&15;
      lds_al[idx] = alpha[(size_t)lds_e[j]*BB + bq*16 + b2];
    }
    __syncthreads();
    #pragma unroll 4
    for (int j=0;j<tl;++j){
      int n = lds_n[j];
      float al = lds_al[j*16+bi];
      float4 v = *(const float4*)&outf[(size_t)b*(NN*CC) + (size_t)n*CC + c0];
      as.x+=v.x; as.y+=v.y; as.z+=v.z; as.w+=v.w;
      af.x+=al*v.x; af.y+=al*v.y; af.z+=al*v.z; af.w+=al*v.w;
    }
  }
  float bn = deg>0 ? 1.f/(float)deg : 0.f;
  size_t o = ((size_t)m*BB+b)*CC+c0;
  *(float4*)&es[o]=as;
  float4 f; f.x=af.x*bn; f.y=af.y*bn; f.z=af.z*bn; f.w=af.w*bn;
  *(float4*)&ef[o]=f;
  float ssq = as.x*as.x+as.y*as.y+as.z*as.z+as.w*as.w;
  for (int s=8;s>=1;s>>=1) ssq += __shfl_xor(ssq,s,64);
  if ((t&15)==0) nrm[m*BB+b] = ssq>0.f? sqrtf(ssq):0.f;
}

// ---- pairwise hyperedge loss, one block per (k,m), lane = batch
__global__ void k_pair(const float* __restrict__ es,const float* __restrict__ nrm,
                       float* __restrict__ pairl){
  int kk = blockIdx.x / MM, m = blockIdx.x % MM;
  int b = threadIdx.x;
  const float4* pa = (const float4*)&es[((size_t)kk*BB+b)*CC];
  const float4* pb = (const float4*)&es[((size_t)m*BB+b)*CC];
  float inner=0.f, d2=0.f;
  #pragma unroll
  for (int q=0;q<16;++q){
    float4 a=pa[q], c=pb[q];
    inner += a.x*c.x+a.y*c.y+a.z*c.z+a.w*c.w;
    float dx=a.x-c.x, dy=a.y-c.y, dz=a.z-c.z, dw=a.w-c.w;
    d2 += dx*dx+dy*dy+dz*dz+dw*dw;
  }
  float dist = d2>0.f? sqrtf(d2):0.f;
  float cosv = inner/(nrm[kk*BB+b]*nrm[m*BB+b]);
  float li = cosv*dist + (1.f-cosv)*fmaxf(MARGIN_-dist,0.f);
  for (int s=32;s>=1;s>>=1) li += __shfl_xor(li,s,64);
  if (b==0) pairl[blockIdx.x] = fabsf(li*(1.f/64.f));
}

// ---- out[b,n,c] = D[n] * sum_{e in n} alpha[e,b]*ef[edge[e],b,c]; overwrites xw stage
__global__ void k_out(const int* __restrict__ nlist,const int* __restrict__ noff,
                      const int* __restrict__ ncnt,const int* __restrict__ eidx,
                      const float* __restrict__ alpha,const float* __restrict__ ef,
                      float* __restrict__ outf){
  int n = blockIdx.x, t = threadIdx.x;
  int b = t>>2, sub = t&3;           // 16 floats per thread
  int off = noff[n], deg = ncnt[n];
  float4 a0=make_float4(0.f,0.f,0.f,0.f),a1=a0,a2=a0,a3=a0;
  for (int j=0;j<deg;++j){
    int e = nlist[off+j]; int m = eidx[e];
    float al = alpha[(size_t)e*BB+b];
    const float4* p = (const float4*)&ef[((size_t)m*BB+b)*CC + sub*16];
    float4 v0=p[0],v1=p[1],v2=p[2],v3=p[3];
    a0.x+=al*v0.x; a0.y+=al*v0.y; a0.z+=al*v0.z; a0.w+=al*v0.w;
    a1.x+=al*v1.x; a1.y+=al*v1.y; a1.z+=al*v1.z; a1.w+=al*v1.w;
    a2.x+=al*v2.x; a2.y+=al*v2.y; a2.z+=al*v2.z; a2.w+=al*v2.w;
    a3.x+=al*v3.x; a3.y+=al*v3.y; a3.z+=al*v3.z; a3.w+=al*v3.w;
  }
  float D=(float)deg;
  float* o = &outf[(size_t)b*(NN*CC) + (size_t)n*CC + sub*16];
  float4 w0=make_float4(D*a0.x,D*a0.y,D*a0.z,D*a0.w);
  float4 w1=make_float4(D*a1.x,D*a1.y,D*a1.z,D*a1.w);
  float4 w2=make_float4(D*a2.x,D*a2.y,D*a2.z,D*a2.w);
  float4 w3=make_float4(D*a3.x,D*a3.y,D*a3.z,D*a3.w);
  ((float4*)o)[0]=w0; ((float4*)o)[1]=w1; ((float4*)o)[2]=w2; ((float4*)o)[3]=w3;
}

// ---- loss reduction stage 1: 256 blocks, fixed strided partition (deterministic)
__global__ __launch_bounds__(256) void k_lred(const float* __restrict__ pairl,
                       const float* __restrict__ rowsum,const int* __restrict__ ncnt,
                       const float* __restrict__ es,const int* __restrict__ ecnt,
                       float* __restrict__ partial){
  __shared__ float r1[256],r2[256],r3[256];
  int t=threadIdx.x;
  int gid = blockIdx.x*256+t, stride = 256*256;
  float s1=0.f,s2=0.f,s3=0.f;
  for (int i=gid;i<MM*MM;i+=stride)    s1+=pairl[i];
  for (int i=gid;i<NN;i+=stride)       s2+=rowsum[i]*(float)ncnt[i];
  for (int i=gid;i<MM*BB*CC;i+=stride) s3+=es[i]*(float)ecnt[i>>12];
  r1[t]=s1;r2[t]=s2;r3[t]=s3; __syncthreads();
  for (int s=128;s>0;s>>=1){ if(t<s){r1[t]+=r1[t+s];r2[t]+=r2[t+s];r3[t]+=r3[t+s];} __syncthreads(); }
  if (t==0){
    partial[blockIdx.x*3+0]=r1[0];
    partial[blockIdx.x*3+1]=r2[0];
    partial[blockIdx.x*3+2]=r3[0];
  }
}

// ---- loss reduction stage 2: one block over 256 partials
__global__ void k_lfin(const float* __restrict__ partial, float* __restrict__ out){
  __shared__ float r1[256],r2[256],r3[256];
  int t=threadIdx.x;
  r1[t]=partial[t*3+0]; r2[t]=partial[t*3+1]; r3[t]=partial[t*3+2];
  __syncthreads();
  for (int s=128;s>0;s>>=1){ if(t<s){r1[t]+=r1[t+s];r2[t]+=r2[t+s];r3[t]+=r3[t+s];} __syncthreads(); }
  if (t==0){
    float lh = r1[0]/2601.f;                           // /(M+1)^2
    float con = fabsf((r2[0]-r3[0])*(1.f/33554432.f)); // /(E*B*C)
    out[(size_t)NN*BB*CC] = con+lh;
  }
}

extern "C" void kernel_launch(void* const* d_in, const int* in_sizes, int n_in,
                              void* d_out, int out_size, void* d_ws, size_t ws_size,
                              hipStream_t stream){
  (void)in_sizes; (void)n_in; (void)out_size; (void)ws_size;
  const float* x    = (const float*)d_in[0];
  const float* w    = (const float*)d_in[1];
  const float* att  = (const float*)d_in[2];
  const int*   nidx = (const int*)d_in[3];
  const int*   eidx = (const int*)d_in[4];
  float* outf = (float*)d_out;                    // reference outputs are float32

  char* ws = (char*)d_ws;
  size_t off = 0;
  auto alloc = [&](size_t bytes)->void*{ void* p = ws + off; off = (off + bytes + 255) & ~(size_t)255; return p; };
  float* natt1 = (float*)alloc(sizeof(float)*NN*BB);
  float* natt2 = (float*)alloc(sizeof(float)*NN*BB);
  float* eatt2 = (float*)alloc(sizeof(float)*MM*BB);
  float* alpha = (float*)alloc(sizeof(float)*(size_t)EE*BB);
  float* es    = (float*)alloc(sizeof(float)*MM*BB*CC);
  float* ef    = (float*)alloc(sizeof(float)*MM*BB*CC);
  float* nrm   = (float*)alloc(sizeof(float)*MM*BB);
  float* pairl = (float*)alloc(sizeof(float)*MM*MM);
  float* rowsum= (float*)alloc(sizeof(float)*NN);
  float* partial=(float*)alloc(sizeof(float)*256*3);
  int* ncnt = (int*)alloc(sizeof(int)*NN);
  int* noff = (int*)alloc(sizeof(int)*NN);
  int* ecnt = (int*)alloc(sizeof(int)*MM);
  int* eoff = (int*)alloc(sizeof(int)*MM);
  int* nlist= (int*)alloc(sizeof(int)*EE);
  int* elist= (int*)alloc(sizeof(int)*EE);
  // total ~4.4 MB

  k_counts <<<NN+MM, 256, 0, stream>>>(nidx, eidx, ncnt, ecnt);
  k_offsets<<<1, 256, 0, stream>>>(ncnt, ecnt, noff, eoff);
  k_build  <<<NN+MM, 64, 0, stream>>>(nidx, eidx, noff, eoff, nlist, elist);
  k_gemm   <<<(NN*BB)/16, 256, 0, stream>>>(x, w, att, outf, natt1, natt2);
  k_rowsum <<<NN, 64, 0, stream>>>(outf, rowsum);
  k_eatt   <<<MM, 256, 0, stream>>>(elist, eoff, ecnt, nidx, natt2, eatt2);
  k_alpha  <<<NN, 64, 0, stream>>>(nlist, noff, ncnt, eidx, natt1, eatt2, alpha);
  k_edge   <<<MM*4, 256, 0, stream>>>(elist, eoff, ecnt, nidx, outf, alpha, es, ef, nrm);
  k_pair   <<<MM*MM, 64, 0, stream>>>(es, nrm, pairl);
  k_out    <<<NN, 256, 0, stream>>>(nlist, noff, ncnt, eidx, alpha, ef, outf);
  k_lred   <<<256, 256, 0, stream>>>(pairl, rowsum, ncnt, es, ecnt, partial);
  k_lfin   <<<1, 256, 0, stream>>>(partial, outf);
}

// Round 8
// 171.463 us; speedup vs baseline: 2.7398x; 1.0235x over previous
//
#include <hip/hip_runtime.h>
#include <math.h>

#define NN 2048
#define MM 50
#define CC 64
#define BB 64
#define EE 8192
#define NEG 0.2f
#define MARGIN_ 4.2f
#define ETILE 320   // max incidences staged per tile

// ---- counts: one block per segment scans all E indices (deterministic, no atomics)
__global__ void k_counts(const int* __restrict__ nidx, const int* __restrict__ eidx,
                         int* __restrict__ ncnt, int* __restrict__ ecnt){
  __shared__ int red[256];
  int seg = blockIdx.x, t = threadIdx.x;
  int c = 0;
  if (seg < NN){
    for (int e=t;e<EE;e+=256) c += (nidx[e]==seg);
  } else {
    int m = seg-NN;
    for (int e=t;e<EE;e+=256) c += (eidx[e]==m);
  }
  red[t]=c; __syncthreads();
  for (int s=128;s>0;s>>=1){ if(t<s) red[t]+=red[t+s]; __syncthreads(); }
  if (t==0){ if (seg<NN) ncnt[seg]=red[0]; else ecnt[seg-NN]=red[0]; }
}

// ---- exclusive prefix sums (single block)
__global__ void k_offsets(const int* __restrict__ ncnt,const int* __restrict__ ecnt,
                          int* __restrict__ noff,int* __restrict__ eoff){
  __shared__ int buf[256];
  __shared__ int carry;
  int t=threadIdx.x;
  if (t==0) carry=0;
  __syncthreads();
  for (int base=0;base<NN;base+=256){
    int v = ncnt[base+t];
    buf[t]=v; __syncthreads();
    for (int o=1;o<256;o<<=1){
      int x=(t>=o)?buf[t-o]:0; __syncthreads();
      buf[t]+=x; __syncthreads();
    }
    int c = carry;
    noff[base+t] = c + buf[t]-v;
    __syncthreads();
    if (t==0) carry = c + buf[255];
    __syncthreads();
  }
  int v = (t<MM)? ecnt[t]:0;
  buf[t]=v; __syncthreads();
  for (int o=1;o<256;o<<=1){
    int x=(t>=o)?buf[t-o]:0; __syncthreads();
    buf[t]+=x; __syncthreads();
  }
  if (t<MM) eoff[t]=buf[t]-v;
}

// ---- stable CSR compaction: one wave per segment, ballot-ranked (deterministic)
__global__ void k_build(const int* __restrict__ nidx,const int* __restrict__ eidx,
                        const int* __restrict__ noff,const int* __restrict__ eoff,
                        int* __restrict__ nlist,int* __restrict__ elist){
  int seg = blockIdx.x;
  int lane = threadIdx.x;           // 64 lanes = 1 wave
  const int* key; int target, base; int* outl;
  if (seg < NN){ key=nidx; target=seg;     base=noff[seg];     outl=nlist; }
  else         { key=eidx; target=seg-NN;  base=eoff[seg-NN];  outl=elist; }
  int carry = 0;
  unsigned long long ltmask = (1ull<<lane) - 1ull;
  for (int w=0; w<EE/64; ++w){
    int e = w*64 + lane;
    bool m = (key[e]==target);
    unsigned long long bal = __ballot(m);
    if (m){
      int pos = __popcll(bal & ltmask);
      outl[base + carry + pos] = e;
    }
    carry += __popcll(bal);
  }
}

// ---- xw = x @ W, register-accumulator, W/att via wave-uniform scalar loads.
//      One thread = one (b,n) row. Fuses natt1/natt2 and per-row sum rsBN.
//      xw staged into d_out (same [B,N,C] layout).
__global__ __launch_bounds__(256) void k_gemm(const float* __restrict__ x,const float* __restrict__ w,
       const float* __restrict__ att, float* __restrict__ outf,
       float* __restrict__ natt1,float* __restrict__ natt2,float* __restrict__ rsBN){
  int rid = blockIdx.x*256 + threadIdx.x;       // rid = b*NN + n
  const float4* xr = (const float4*)(x + (size_t)rid*CC);
  float acc[CC];
  #pragma unroll
  for (int c=0;c<CC;++c) acc[c]=0.f;
  #pragma unroll 1
  for (int k4=0;k4<CC/4;++k4){
    float4 xv = xr[k4];
    float xs[4] = {xv.x, xv.y, xv.z, xv.w};
    #pragma unroll
    for (int kk=0;kk<4;++kk){
      float a = xs[kk];
      int k = k4*4+kk;
      #pragma unroll
      for (int c4=0;c4<CC/4;++c4){
        float4 wv = *(const float4*)(w + k*CC + c4*4);   // uniform -> SGPR broadcast
        acc[c4*4+0] += a*wv.x; acc[c4*4+1] += a*wv.y;
        acc[c4*4+2] += a*wv.z; acc[c4*4+3] += a*wv.w;
      }
    }
  }
  // write xw row
  float4* orow = (float4*)(outf + (size_t)rid*CC);
  #pragma unroll
  for (int c4=0;c4<CC/4;++c4)
    orow[c4] = make_float4(acc[c4*4],acc[c4*4+1],acc[c4*4+2],acc[c4*4+3]);
  // fused att dots + row sum
  float a1=0.f, a2=0.f, rs=0.f;
  #pragma unroll
  for (int c4=0;c4<CC/4;++c4){
    float4 v1 = *(const float4*)(att + c4*4);        // uniform
    float4 v2 = *(const float4*)(att + CC + c4*4);   // uniform
    a1 += acc[c4*4]*v1.x + acc[c4*4+1]*v1.y + acc[c4*4+2]*v1.z + acc[c4*4+3]*v1.w;
    a2 += acc[c4*4]*v2.x + acc[c4*4+1]*v2.y + acc[c4*4+2]*v2.z + acc[c4*4+3]*v2.w;
    rs += (acc[c4*4]+acc[c4*4+1]) + (acc[c4*4+2]+acc[c4*4+3]);
  }
  int b = rid>>11, n = rid&(NN-1);
  natt1[n*BB+b]=a1; natt2[n*BB+b]=a2; rsBN[rid]=rs;
}

// ---- eatt2[m,b] = sum_{e in m} natt2[node[e],b]  -- LDS-staged, 4-chunk ILP
__global__ __launch_bounds__(256) void k_eatt(const int* __restrict__ elist,const int* __restrict__ eoff,
                       const int* __restrict__ ecnt,const int* __restrict__ nidx,
                       const float* __restrict__ natt2,float* __restrict__ eatt2){
  __shared__ int lds_n[ETILE];
  __shared__ float part[256];
  int m=blockIdx.x, t=threadIdx.x;
  int b = t&63, ck = t>>6;                 // 4 chunks
  int off=eoff[m], deg=ecnt[m];
  float s=0.f;
  for (int tb=0; tb<deg; tb+=ETILE){
    int tl = min(ETILE, deg-tb);
    __syncthreads();
    for (int j=t;j<tl;j+=256) lds_n[j]=nidx[elist[off+tb+j]];
    __syncthreads();
    int j0=(tl*ck)>>2, j1=(tl*(ck+1))>>2;
    for (int j=j0;j<j1;++j) s += natt2[lds_n[j]*BB+b];
  }
  part[t]=s; __syncthreads();
  if (t<64) eatt2[m*BB+b] = (part[b]+part[64+b])+(part[128+b]+part[192+b]);
}

// ---- grouped softmax per node (1 wave per node, lane = batch)
__global__ void k_alpha(const int* __restrict__ nlist,const int* __restrict__ noff,
                        const int* __restrict__ ncnt,const int* __restrict__ eidx,
                        const float* __restrict__ natt1,const float* __restrict__ eatt2,
                        float* __restrict__ alpha){
  int n = blockIdx.x, b = threadIdx.x;
  int off = noff[n], deg = ncnt[n];
  if (deg==0) return;
  float na = natt1[n*BB+b];
  float mx = -1e30f;
  for (int j=0;j<deg;++j){
    int e = nlist[off+j]; int m = eidx[e];
    float l = na + eatt2[m*BB+b]; l = l>0.f? l : NEG*l;
    mx = fmaxf(mx,l);
  }
  float s=0.f;
  for (int j=0;j<deg;++j){
    int e = nlist[off+j]; int m = eidx[e];
    float l = na + eatt2[m*BB+b]; l = l>0.f? l : NEG*l;
    s += expf(l-mx);
  }
  float inv = 1.f/(s+1e-16f);
  for (int j=0;j<deg;++j){
    int e = nlist[off+j]; int m = eidx[e];
    float l = na + eatt2[m*BB+b]; l = l>0.f? l : NEG*l;
    alpha[(size_t)e*BB+b] = expf(l-mx)*inv;
  }
}

// ---- fused per-edge gather: edge_sums, edge_feat, norms -- LDS index/alpha staging
__global__ __launch_bounds__(256) void k_edge(const int* __restrict__ elist,const int* __restrict__ eoff,
                       const int* __restrict__ ecnt,const int* __restrict__ nidx,
                       const float* __restrict__ outf,const float* __restrict__ alpha,
                       float* __restrict__ es,float* __restrict__ ef,float* __restrict__ nrm){
  __shared__ int   lds_e[ETILE];
  __shared__ int   lds_n[ETILE];
  __shared__ float lds_al[ETILE*16];
  int m = blockIdx.x>>2, bq = blockIdx.x&3;
  int t = threadIdx.x;
  int bi = t>>4;                 // 0..15
  int b  = bq*16 + bi;
  int c0 = (t&15)*4;
  int off = eoff[m], deg = ecnt[m];
  float4 as=make_float4(0.f,0.f,0.f,0.f), af=as;
  for (int tb=0; tb<deg; tb+=ETILE){
    int tl = min(ETILE, deg-tb);
    __syncthreads();                               // previous tile fully consumed
    for (int j=t;j<tl;j+=256){
      int e = elist[off+tb+j];
      lds_e[j]=e; lds_n[j]=nidx[e];
    }
    __syncthreads();
    for (int idx=t; idx<tl*16; idx+=256){
      int j=idx>>4, b2=idx&15;
      lds_al[idx] = alpha[(size_t)lds_e[j]*BB + bq*16 + b2];
    }
    __syncthreads();
    #pragma unroll 4
    for (int j=0;j<tl;++j){
      int n = lds_n[j];
      float al = lds_al[j*16+bi];
      float4 v = *(const float4*)&outf[(size_t)b*(NN*CC) + (size_t)n*CC + c0];
      as.x+=v.x; as.y+=v.y; as.z+=v.z; as.w+=v.w;
      af.x+=al*v.x; af.y+=al*v.y; af.z+=al*v.z; af.w+=al*v.w;
    }
  }
  float bn = deg>0 ? 1.f/(float)deg : 0.f;
  size_t o = ((size_t)m*BB+b)*CC+c0;
  *(float4*)&es[o]=as;
  float4 f; f.x=af.x*bn; f.y=af.y*bn; f.z=af.z*bn; f.w=af.w*bn;
  *(float4*)&ef[o]=f;
  float ssq = as.x*as.x+as.y*as.y+as.z*as.z+as.w*as.w;
  for (int s=8;s>=1;s>>=1) ssq += __shfl_xor(ssq,s,64);
  if ((t&15)==0) nrm[m*BB+b] = ssq>0.f? sqrtf(ssq):0.f;
}

// ---- pairwise hyperedge loss, one block per (k,m), lane = batch
__global__ void k_pair(const float* __restrict__ es,const float* __restrict__ nrm,
                       float* __restrict__ pairl){
  int kk = blockIdx.x / MM, m = blockIdx.x % MM;
  int b = threadIdx.x;
  const float4* pa = (const float4*)&es[((size_t)kk*BB+b)*CC];
  const float4* pb = (const float4*)&es[((size_t)m*BB+b)*CC];
  float inner=0.f, d2=0.f;
  #pragma unroll
  for (int q=0;q<16;++q){
    float4 a=pa[q], c=pb[q];
    inner += a.x*c.x+a.y*c.y+a.z*c.z+a.w*c.w;
    float dx=a.x-c.x, dy=a.y-c.y, dz=a.z-c.z, dw=a.w-c.w;
    d2 += dx*dx+dy*dy+dz*dz+dw*dw;
  }
  float dist = d2>0.f? sqrtf(d2):0.f;
  float cosv = inner/(nrm[kk*BB+b]*nrm[m*BB+b]);
  float li = cosv*dist + (1.f-cosv)*fmaxf(MARGIN_-dist,0.f);
  for (int s=32;s>=1;s>>=1) li += __shfl_xor(li,s,64);
  if (b==0) pairl[blockIdx.x] = fabsf(li*(1.f/64.f));
}

// ---- out[b,n,c] = D[n] * sum_{e in n} alpha[e,b]*ef[edge[e],b,c]; overwrites xw stage
__global__ void k_out(const int* __restrict__ nlist,const int* __restrict__ noff,
                      const int* __restrict__ ncnt,const int* __restrict__ eidx,
                      const float* __restrict__ alpha,const float* __restrict__ ef,
                      float* __restrict__ outf){
  int n = blockIdx.x, t = threadIdx.x;
  int b = t>>2, sub = t&3;           // 16 floats per thread
  int off = noff[n], deg = ncnt[n];
  float4 a0=make_float4(0.f,0.f,0.f,0.f),a1=a0,a2=a0,a3=a0;
  for (int j=0;j<deg;++j){
    int e = nlist[off+j]; int m = eidx[e];
    float al = alpha[(size_t)e*BB+b];
    const float4* p = (const float4*)&ef[((size_t)m*BB+b)*CC + sub*16];
    float4 v0=p[0],v1=p[1],v2=p[2],v3=p[3];
    a0.x+=al*v0.x; a0.y+=al*v0.y; a0.z+=al*v0.z; a0.w+=al*v0.w;
    a1.x+=al*v1.x; a1.y+=al*v1.y; a1.z+=al*v1.z; a1.w+=al*v1.w;
    a2.x+=al*v2.x; a2.y+=al*v2.y; a2.z+=al*v2.z; a2.w+=al*v2.w;
    a3.x+=al*v3.x; a3.y+=al*v3.y; a3.z+=al*v3.z; a3.w+=al*v3.w;
  }
  float D=(float)deg;
  float* o = &outf[(size_t)b*(NN*CC) + (size_t)n*CC + sub*16];
  float4 w0=make_float4(D*a0.x,D*a0.y,D*a0.z,D*a0.w);
  float4 w1=make_float4(D*a1.x,D*a1.y,D*a1.z,D*a1.w);
  float4 w2=make_float4(D*a2.x,D*a2.y,D*a2.z,D*a2.w);
  float4 w3=make_float4(D*a3.x,D*a3.y,D*a3.z,D*a3.w);
  ((float4*)o)[0]=w0; ((float4*)o)[1]=w1; ((float4*)o)[2]=w2; ((float4*)o)[3]=w3;
}

// ---- loss reduction stage 1: 256 blocks, fixed strided partition (deterministic)
//      s2 now reads per-(b,n)-row sums rsBN (0.5 MB) instead of re-reading xw (33.5 MB)
__global__ __launch_bounds__(256) void k_lred(const float* __restrict__ pairl,
                       const float* __restrict__ rsBN,const int* __restrict__ ncnt,
                       const float* __restrict__ es,const int* __restrict__ ecnt,
                       float* __restrict__ partial){
  __shared__ float r1[256],r2[256],r3[256];
  int t=threadIdx.x;
  int gid = blockIdx.x*256+t, stride = 256*256;
  float s1=0.f,s2=0.f,s3=0.f;
  for (int i=gid;i<MM*MM;i+=stride)    s1+=pairl[i];
  for (int i=gid;i<NN*BB;i+=stride)    s2+=rsBN[i]*(float)ncnt[i&(NN-1)];
  for (int i=gid;i<MM*BB*CC;i+=stride) s3+=es[i]*(float)ecnt[i>>12];
  r1[t]=s1;r2[t]=s2;r3[t]=s3; __syncthreads();
  for (int s=128;s>0;s>>=1){ if(t<s){r1[t]+=r1[t+s];r2[t]+=r2[t+s];r3[t]+=r3[t+s];} __syncthreads(); }
  if (t==0){
    partial[blockIdx.x*3+0]=r1[0];
    partial[blockIdx.x*3+1]=r2[0];
    partial[blockIdx.x*3+2]=r3[0];
  }
}

// ---- loss reduction stage 2: one block over 256 partials
__global__ void k_lfin(const float* __restrict__ partial, float* __restrict__ out){
  __shared__ float r1[256],r2[256],r3[256];
  int t=threadIdx.x;
  r1[t]=partial[t*3+0]; r2[t]=partial[t*3+1]; r3[t]=partial[t*3+2];
  __syncthreads();
  for (int s=128;s>0;s>>=1){ if(t<s){r1[t]+=r1[t+s];r2[t]+=r2[t+s];r3[t]+=r3[t+s];} __syncthreads(); }
  if (t==0){
    float lh = r1[0]/2601.f;                           // /(M+1)^2
    float con = fabsf((r2[0]-r3[0])*(1.f/33554432.f)); // /(E*B*C)
    out[(size_t)NN*BB*CC] = con+lh;
  }
}

extern "C" void kernel_launch(void* const* d_in, const int* in_sizes, int n_in,
                              void* d_out, int out_size, void* d_ws, size_t ws_size,
                              hipStream_t stream){
  (void)in_sizes; (void)n_in; (void)out_size; (void)ws_size;
  const float* x    = (const float*)d_in[0];
  const float* w    = (const float*)d_in[1];
  const float* att  = (const float*)d_in[2];
  const int*   nidx = (const int*)d_in[3];
  const int*   eidx = (const int*)d_in[4];
  float* outf = (float*)d_out;                    // reference outputs are float32

  char* ws = (char*)d_ws;
  size_t off = 0;
  auto alloc = [&](size_t bytes)->void*{ void* p = ws + off; off = (off + bytes + 255) & ~(size_t)255; return p; };
  float* natt1 = (float*)alloc(sizeof(float)*NN*BB);
  float* natt2 = (float*)alloc(sizeof(float)*NN*BB);
  float* eatt2 = (float*)alloc(sizeof(float)*MM*BB);
  float* alpha = (float*)alloc(sizeof(float)*(size_t)EE*BB);
  float* es    = (float*)alloc(sizeof(float)*MM*BB*CC);
  float* ef    = (float*)alloc(sizeof(float)*MM*BB*CC);
  float* nrm   = (float*)alloc(sizeof(float)*MM*BB);
  float* pairl = (float*)alloc(sizeof(float)*MM*MM);
  float* rsBN  = (float*)alloc(sizeof(float)*NN*BB);
  float* partial=(float*)alloc(sizeof(float)*256*3);
  int* ncnt = (int*)alloc(sizeof(int)*NN);
  int* noff = (int*)alloc(sizeof(int)*NN);
  int* ecnt = (int*)alloc(sizeof(int)*MM);
  int* eoff = (int*)alloc(sizeof(int)*MM);
  int* nlist= (int*)alloc(sizeof(int)*EE);
  int* elist= (int*)alloc(sizeof(int)*EE);
  // total ~5 MB

  k_counts <<<NN+MM, 256, 0, stream>>>(nidx, eidx, ncnt, ecnt);
  k_offsets<<<1, 256, 0, stream>>>(ncnt, ecnt, noff, eoff);
  k_build  <<<NN+MM, 64, 0, stream>>>(nidx, eidx, noff, eoff, nlist, elist);
  k_gemm   <<<(NN*BB)/256, 256, 0, stream>>>(x, w, att, outf, natt1, natt2, rsBN);
  k_eatt   <<<MM, 256, 0, stream>>>(elist, eoff, ecnt, nidx, natt2, eatt2);
  k_alpha  <<<NN, 64, 0, stream>>>(nlist, noff, ncnt, eidx, natt1, eatt2, alpha);
  k_edge   <<<MM*4, 256, 0, stream>>>(elist, eoff, ecnt, nidx, outf, alpha, es, ef, nrm);
  k_pair   <<<MM*MM, 64, 0, stream>>>(es, nrm, pairl);
  k_out    <<<NN, 256, 0, stream>>>(nlist, noff, ncnt, eidx, alpha, ef, outf);
  k_lred   <<<256, 256, 0, stream>>>(pairl, rsBN, ncnt, es, ecnt, partial);
  k_lfin   <<<1, 256, 0, stream>>>(partial, outf);
}

// Round 9
// 158.199 us; speedup vs baseline: 2.9695x; 1.0838x over previous
//
#include <hip/hip_runtime.h>
#include <math.h>

#define NN 2048
#define MM 50
#define CC 64
#define BB 64
#define EE 8192
#define NEG 0.2f
#define MARGIN_ 4.2f
#define ETILE 320   // max incidences staged per tile

// ---- counts: one block per segment scans all E indices (deterministic, no atomics)
__global__ void k_counts(const int* __restrict__ nidx, const int* __restrict__ eidx,
                         int* __restrict__ ncnt, int* __restrict__ ecnt){
  __shared__ int red[256];
  int seg = blockIdx.x, t = threadIdx.x;
  int c = 0;
  if (seg < NN){
    for (int e=t;e<EE;e+=256) c += (nidx[e]==seg);
  } else {
    int m = seg-NN;
    for (int e=t;e<EE;e+=256) c += (eidx[e]==m);
  }
  red[t]=c; __syncthreads();
  for (int s=128;s>0;s>>=1){ if(t<s) red[t]+=red[t+s]; __syncthreads(); }
  if (t==0){ if (seg<NN) ncnt[seg]=red[0]; else ecnt[seg-NN]=red[0]; }
}

// ---- exclusive prefix sums (single block)
__global__ void k_offsets(const int* __restrict__ ncnt,const int* __restrict__ ecnt,
                          int* __restrict__ noff,int* __restrict__ eoff){
  __shared__ int buf[256];
  __shared__ int carry;
  int t=threadIdx.x;
  if (t==0) carry=0;
  __syncthreads();
  for (int base=0;base<NN;base+=256){
    int v = ncnt[base+t];
    buf[t]=v; __syncthreads();
    for (int o=1;o<256;o<<=1){
      int x=(t>=o)?buf[t-o]:0; __syncthreads();
      buf[t]+=x; __syncthreads();
    }
    int c = carry;
    noff[base+t] = c + buf[t]-v;
    __syncthreads();
    if (t==0) carry = c + buf[255];
    __syncthreads();
  }
  int v = (t<MM)? ecnt[t]:0;
  buf[t]=v; __syncthreads();
  for (int o=1;o<256;o<<=1){
    int x=(t>=o)?buf[t-o]:0; __syncthreads();
    buf[t]+=x; __syncthreads();
  }
  if (t<MM) eoff[t]=buf[t]-v;
}

// ---- stable CSR compaction: one wave per segment, ballot-ranked (deterministic)
__global__ void k_build(const int* __restrict__ nidx,const int* __restrict__ eidx,
                        const int* __restrict__ noff,const int* __restrict__ eoff,
                        int* __restrict__ nlist,int* __restrict__ elist){
  int seg = blockIdx.x;
  int lane = threadIdx.x;           // 64 lanes = 1 wave
  const int* key; int target, base; int* outl;
  if (seg < NN){ key=nidx; target=seg;     base=noff[seg];     outl=nlist; }
  else         { key=eidx; target=seg-NN;  base=eoff[seg-NN];  outl=elist; }
  int carry = 0;
  unsigned long long ltmask = (1ull<<lane) - 1ull;
  for (int w=0; w<EE/64; ++w){
    int e = w*64 + lane;
    bool m = (key[e]==target);
    unsigned long long bal = __ballot(m);
    if (m){
      int pos = __popcll(bal & ltmask);
      outl[base + carry + pos] = e;
    }
    carry += __popcll(bal);
  }
}

// ---- xw = x @ W : register-tiled 4x4 per thread, LDS-staged X(+pad)/W.
//      Block = 64 rows x 64 cols. Fuses natt1/natt2 (att dots) and row sums rsBN.
//      xw staged into d_out (same [B,N,C] layout).
__global__ __launch_bounds__(256) void k_gemm(const float* __restrict__ x,const float* __restrict__ w,
       const float* __restrict__ att, float* __restrict__ outf,
       float* __restrict__ natt1,float* __restrict__ natt2,float* __restrict__ rsBN){
  __shared__ float Xl[64*68];          // stride 68 breaks bank aliasing
  __shared__ float Wl[64*64];          // [k][c], k-major
  int t = threadIdx.x;
  size_t rbase = (size_t)blockIdx.x*64;
  {
    const float4* xs = (const float4*)(x + rbase*CC);
    const float4* wsrc = (const float4*)w;
    #pragma unroll
    for (int i=0;i<4;++i){
      int idx = t + i*256;             // 0..1023
      int r = idx>>4, c4 = idx&15;
      float4 v = xs[idx];
      *(float4*)&Xl[r*68 + c4*4] = v;
      ((float4*)Wl)[idx] = wsrc[idx];
    }
  }
  __syncthreads();
  int rg = t>>4, cg = t&15;
  int c0 = cg*4;
  float acc[4][4];
  #pragma unroll
  for (int i=0;i<4;++i){ acc[i][0]=0.f; acc[i][1]=0.f; acc[i][2]=0.f; acc[i][3]=0.f; }
  #pragma unroll
  for (int ks=0; ks<16; ++ks){
    int k0 = ks*4;
    float4 Wf0 = *(const float4*)&Wl[(k0+0)*64 + c0];
    float4 Wf1 = *(const float4*)&Wl[(k0+1)*64 + c0];
    float4 Wf2 = *(const float4*)&Wl[(k0+2)*64 + c0];
    float4 Wf3 = *(const float4*)&Wl[(k0+3)*64 + c0];
    #pragma unroll
    for (int ri=0;ri<4;++ri){
      float4 Xf = *(const float4*)&Xl[(rg*4+ri)*68 + k0];
      acc[ri][0] += Xf.x*Wf0.x; acc[ri][1] += Xf.x*Wf0.y; acc[ri][2] += Xf.x*Wf0.z; acc[ri][3] += Xf.x*Wf0.w;
      acc[ri][0] += Xf.y*Wf1.x; acc[ri][1] += Xf.y*Wf1.y; acc[ri][2] += Xf.y*Wf1.z; acc[ri][3] += Xf.y*Wf1.w;
      acc[ri][0] += Xf.z*Wf2.x; acc[ri][1] += Xf.z*Wf2.y; acc[ri][2] += Xf.z*Wf2.z; acc[ri][3] += Xf.z*Wf2.w;
      acc[ri][0] += Xf.w*Wf3.x; acc[ri][1] += Xf.w*Wf3.y; acc[ri][2] += Xf.w*Wf3.z; acc[ri][3] += Xf.w*Wf3.w;
    }
  }
  // write xw rows (coalesced float4)
  #pragma unroll
  for (int ri=0;ri<4;++ri){
    size_t row = rbase + rg*4 + ri;
    *(float4*)&outf[row*CC + c0] = make_float4(acc[ri][0],acc[ri][1],acc[ri][2],acc[ri][3]);
  }
  // fused att dots + row sums: partial over this thread's 4 cols, reduce across 16 cg lanes
  float4 at1 = *(const float4*)(att + c0);
  float4 at2 = *(const float4*)(att + CC + c0);
  #pragma unroll
  for (int ri=0;ri<4;++ri){
    float a1 = acc[ri][0]*at1.x + acc[ri][1]*at1.y + acc[ri][2]*at1.z + acc[ri][3]*at1.w;
    float a2 = acc[ri][0]*at2.x + acc[ri][1]*at2.y + acc[ri][2]*at2.z + acc[ri][3]*at2.w;
    float rs = (acc[ri][0]+acc[ri][1]) + (acc[ri][2]+acc[ri][3]);
    #pragma unroll
    for (int m=8;m>=1;m>>=1){
      a1 += __shfl_xor(a1,m,64);
      a2 += __shfl_xor(a2,m,64);
      rs += __shfl_xor(rs,m,64);
    }
    if (cg==0){
      size_t row = rbase + rg*4 + ri;
      int b = (int)(row>>11), n = (int)(row&(NN-1));
      natt1[n*BB+b]=a1; natt2[n*BB+b]=a2; rsBN[row]=rs;
    }
  }
}

// ---- eatt2[m,b] = sum_{e in m} natt2[node[e],b]  -- LDS-staged, 4-chunk ILP
__global__ __launch_bounds__(256) void k_eatt(const int* __restrict__ elist,const int* __restrict__ eoff,
                       const int* __restrict__ ecnt,const int* __restrict__ nidx,
                       const float* __restrict__ natt2,float* __restrict__ eatt2){
  __shared__ int lds_n[ETILE];
  __shared__ float part[256];
  int m=blockIdx.x, t=threadIdx.x;
  int b = t&63, ck = t>>6;                 // 4 chunks
  int off=eoff[m], deg=ecnt[m];
  float s=0.f;
  for (int tb=0; tb<deg; tb+=ETILE){
    int tl = min(ETILE, deg-tb);
    __syncthreads();
    for (int j=t;j<tl;j+=256) lds_n[j]=nidx[elist[off+tb+j]];
    __syncthreads();
    int j0=(tl*ck)>>2, j1=(tl*(ck+1))>>2;
    for (int j=j0;j<j1;++j) s += natt2[lds_n[j]*BB+b];
  }
  part[t]=s; __syncthreads();
  if (t<64) eatt2[m*BB+b] = (part[b]+part[64+b])+(part[128+b]+part[192+b]);
}

// ---- grouped softmax per node (1 wave per node, lane = batch)
__global__ void k_alpha(const int* __restrict__ nlist,const int* __restrict__ noff,
                        const int* __restrict__ ncnt,const int* __restrict__ eidx,
                        const float* __restrict__ natt1,const float* __restrict__ eatt2,
                        float* __restrict__ alpha){
  int n = blockIdx.x, b = threadIdx.x;
  int off = noff[n], deg = ncnt[n];
  if (deg==0) return;
  float na = natt1[n*BB+b];
  float mx = -1e30f;
  for (int j=0;j<deg;++j){
    int e = nlist[off+j]; int m = eidx[e];
    float l = na + eatt2[m*BB+b]; l = l>0.f? l : NEG*l;
    mx = fmaxf(mx,l);
  }
  float s=0.f;
  for (int j=0;j<deg;++j){
    int e = nlist[off+j]; int m = eidx[e];
    float l = na + eatt2[m*BB+b]; l = l>0.f? l : NEG*l;
    s += expf(l-mx);
  }
  float inv = 1.f/(s+1e-16f);
  for (int j=0;j<deg;++j){
    int e = nlist[off+j]; int m = eidx[e];
    float l = na + eatt2[m*BB+b]; l = l>0.f? l : NEG*l;
    alpha[(size_t)e*BB+b] = expf(l-mx)*inv;
  }
}

// ---- fused per-edge gather: edge_sums, edge_feat, norms -- LDS index/alpha staging
__global__ __launch_bounds__(256) void k_edge(const int* __restrict__ elist,const int* __restrict__ eoff,
                       const int* __restrict__ ecnt,const int* __restrict__ nidx,
                       const float* __restrict__ outf,const float* __restrict__ alpha,
                       float* __restrict__ es,float* __restrict__ ef,float* __restrict__ nrm){
  __shared__ int   lds_e[ETILE];
  __shared__ int   lds_n[ETILE];
  __shared__ float lds_al[ETILE*16];
  int m = blockIdx.x>>2, bq = blockIdx.x&3;
  int t = threadIdx.x;
  int bi = t>>4;                 // 0..15
  int b  = bq*16 + bi;
  int c0 = (t&15)*4;
  int off = eoff[m], deg = ecnt[m];
  float4 as=make_float4(0.f,0.f,0.f,0.f), af=as;
  for (int tb=0; tb<deg; tb+=ETILE){
    int tl = min(ETILE, deg-tb);
    __syncthreads();                               // previous tile fully consumed
    for (int j=t;j<tl;j+=256){
      int e = elist[off+tb+j];
      lds_e[j]=e; lds_n[j]=nidx[e];
    }
    __syncthreads();
    for (int idx=t; idx<tl*16; idx+=256){
      int j=idx>>4, b2=idx&15;
      lds_al[idx] = alpha[(size_t)lds_e[j]*BB + bq*16 + b2];
    }
    __syncthreads();
    #pragma unroll 4
    for (int j=0;j<tl;++j){
      int n = lds_n[j];
      float al = lds_al[j*16+bi];
      float4 v = *(const float4*)&outf[(size_t)b*(NN*CC) + (size_t)n*CC + c0];
      as.x+=v.x; as.y+=v.y; as.z+=v.z; as.w+=v.w;
      af.x+=al*v.x; af.y+=al*v.y; af.z+=al*v.z; af.w+=al*v.w;
    }
  }
  float bn = deg>0 ? 1.f/(float)deg : 0.f;
  size_t o = ((size_t)m*BB+b)*CC+c0;
  *(float4*)&es[o]=as;
  float4 f; f.x=af.x*bn; f.y=af.y*bn; f.z=af.z*bn; f.w=af.w*bn;
  *(float4*)&ef[o]=f;
  float ssq = as.x*as.x+as.y*as.y+as.z*as.z+as.w*as.w;
  for (int s=8;s>=1;s>>=1) ssq += __shfl_xor(ssq,s,64);
  if ((t&15)==0) nrm[m*BB+b] = ssq>0.f? sqrtf(ssq):0.f;
}

// ---- pairwise hyperedge loss, one block per (k,m), lane = batch
__global__ void k_pair(const float* __restrict__ es,const float* __restrict__ nrm,
                       float* __restrict__ pairl){
  int kk = blockIdx.x / MM, m = blockIdx.x % MM;
  int b = threadIdx.x;
  const float4* pa = (const float4*)&es[((size_t)kk*BB+b)*CC];
  const float4* pb = (const float4*)&es[((size_t)m*BB+b)*CC];
  float inner=0.f, d2=0.f;
  #pragma unroll
  for (int q=0;q<16;++q){
    float4 a=pa[q], c=pb[q];
    inner += a.x*c.x+a.y*c.y+a.z*c.z+a.w*c.w;
    float dx=a.x-c.x, dy=a.y-c.y, dz=a.z-c.z, dw=a.w-c.w;
    d2 += dx*dx+dy*dy+dz*dz+dw*dw;
  }
  float dist = d2>0.f? sqrtf(d2):0.f;
  float cosv = inner/(nrm[kk*BB+b]*nrm[m*BB+b]);
  float li = cosv*dist + (1.f-cosv)*fmaxf(MARGIN_-dist,0.f);
  for (int s=32;s>=1;s>>=1) li += __shfl_xor(li,s,64);
  if (b==0) pairl[blockIdx.x] = fabsf(li*(1.f/64.f));
}

// ---- out[b,n,c] = D[n] * sum_{e in n} alpha[e,b]*ef[edge[e],b,c]; overwrites xw stage
__global__ void k_out(const int* __restrict__ nlist,const int* __restrict__ noff,
                      const int* __restrict__ ncnt,const int* __restrict__ eidx,
                      const float* __restrict__ alpha,const float* __restrict__ ef,
                      float* __restrict__ outf){
  int n = blockIdx.x, t = threadIdx.x;
  int b = t>>2, sub = t&3;           // 16 floats per thread
  int off = noff[n], deg = ncnt[n];
  float4 a0=make_float4(0.f,0.f,0.f,0.f),a1=a0,a2=a0,a3=a0;
  for (int j=0;j<deg;++j){
    int e = nlist[off+j]; int m = eidx[e];
    float al = alpha[(size_t)e*BB+b];
    const float4* p = (const float4*)&ef[((size_t)m*BB+b)*CC + sub*16];
    float4 v0=p[0],v1=p[1],v2=p[2],v3=p[3];
    a0.x+=al*v0.x; a0.y+=al*v0.y; a0.z+=al*v0.z; a0.w+=al*v0.w;
    a1.x+=al*v1.x; a1.y+=al*v1.y; a1.z+=al*v1.z; a1.w+=al*v1.w;
    a2.x+=al*v2.x; a2.y+=al*v2.y; a2.z+=al*v2.z; a2.w+=al*v2.w;
    a3.x+=al*v3.x; a3.y+=al*v3.y; a3.z+=al*v3.z; a3.w+=al*v3.w;
  }
  float D=(float)deg;
  float* o = &outf[(size_t)b*(NN*CC) + (size_t)n*CC + sub*16];
  float4 w0=make_float4(D*a0.x,D*a0.y,D*a0.z,D*a0.w);
  float4 w1=make_float4(D*a1.x,D*a1.y,D*a1.z,D*a1.w);
  float4 w2=make_float4(D*a2.x,D*a2.y,D*a2.z,D*a2.w);
  float4 w3=make_float4(D*a3.x,D*a3.y,D*a3.z,D*a3.w);
  ((float4*)o)[0]=w0; ((float4*)o)[1]=w1; ((float4*)o)[2]=w2; ((float4*)o)[3]=w3;
}

// ---- loss reduction stage 1: 256 blocks, fixed strided partition (deterministic)
__global__ __launch_bounds__(256) void k_lred(const float* __restrict__ pairl,
                       const float* __restrict__ rsBN,const int* __restrict__ ncnt,
                       const float* __restrict__ es,const int* __restrict__ ecnt,
                       float* __restrict__ partial){
  __shared__ float r1[256],r2[256],r3[256];
  int t=threadIdx.x;
  int gid = blockIdx.x*256+t, stride = 256*256;
  float s1=0.f,s2=0.f,s3=0.f;
  for (int i=gid;i<MM*MM;i+=stride)    s1+=pairl[i];
  for (int i=gid;i<NN*BB;i+=stride)    s2+=rsBN[i]*(float)ncnt[i&(NN-1)];
  for (int i=gid;i<MM*BB*CC;i+=stride) s3+=es[i]*(float)ecnt[i>>12];
  r1[t]=s1;r2[t]=s2;r3[t]=s3; __syncthreads();
  for (int s=128;s>0;s>>=1){ if(t<s){r1[t]+=r1[t+s];r2[t]+=r2[t+s];r3[t]+=r3[t+s];} __syncthreads(); }
  if (t==0){
    partial[blockIdx.x*3+0]=r1[0];
    partial[blockIdx.x*3+1]=r2[0];
    partial[blockIdx.x*3+2]=r3[0];
  }
}

// ---- loss reduction stage 2: one block over 256 partials
__global__ void k_lfin(const float* __restrict__ partial, float* __restrict__ out){
  __shared__ float r1[256],r2[256],r3[256];
  int t=threadIdx.x;
  r1[t]=partial[t*3+0]; r2[t]=partial[t*3+1]; r3[t]=partial[t*3+2];
  __syncthreads();
  for (int s=128;s>0;s>>=1){ if(t<s){r1[t]+=r1[t+s];r2[t]+=r2[t+s];r3[t]+=r3[t+s];} __syncthreads(); }
  if (t==0){
    float lh = r1[0]/2601.f;                           // /(M+1)^2
    float con = fabsf((r2[0]-r3[0])*(1.f/33554432.f)); // /(E*B*C)
    out[(size_t)NN*BB*CC] = con+lh;
  }
}

extern "C" void kernel_launch(void* const* d_in, const int* in_sizes, int n_in,
                              void* d_out, int out_size, void* d_ws, size_t ws_size,
                              hipStream_t stream){
  (void)in_sizes; (void)n_in; (void)out_size; (void)ws_size;
  const float* x    = (const float*)d_in[0];
  const float* w    = (const float*)d_in[1];
  const float* att  = (const float*)d_in[2];
  const int*   nidx = (const int*)d_in[3];
  const int*   eidx = (const int*)d_in[4];
  float* outf = (float*)d_out;                    // reference outputs are float32

  char* ws = (char*)d_ws;
  size_t off = 0;
  auto alloc = [&](size_t bytes)->void*{ void* p = ws + off; off = (off + bytes + 255) & ~(size_t)255; return p; };
  float* natt1 = (float*)alloc(sizeof(float)*NN*BB);
  float* natt2 = (float*)alloc(sizeof(float)*NN*BB);
  float* eatt2 = (float*)alloc(sizeof(float)*MM*BB);
  float* alpha = (float*)alloc(sizeof(float)*(size_t)EE*BB);
  float* es    = (float*)alloc(sizeof(float)*MM*BB*CC);
  float* ef    = (float*)alloc(sizeof(float)*MM*BB*CC);
  float* nrm   = (float*)alloc(sizeof(float)*MM*BB);
  float* pairl = (float*)alloc(sizeof(float)*MM*MM);
  float* rsBN  = (float*)alloc(sizeof(float)*NN*BB);
  float* partial=(float*)alloc(sizeof(float)*256*3);
  int* ncnt = (int*)alloc(sizeof(int)*NN);
  int* noff = (int*)alloc(sizeof(int)*NN);
  int* ecnt = (int*)alloc(sizeof(int)*MM);
  int* eoff = (int*)alloc(sizeof(int)*MM);
  int* nlist= (int*)alloc(sizeof(int)*EE);
  int* elist= (int*)alloc(sizeof(int)*EE);
  // total ~5 MB

  k_counts <<<NN+MM, 256, 0, stream>>>(nidx, eidx, ncnt, ecnt);
  k_offsets<<<1, 256, 0, stream>>>(ncnt, ecnt, noff, eoff);
  k_build  <<<NN+MM, 64, 0, stream>>>(nidx, eidx, noff, eoff, nlist, elist);
  k_gemm   <<<(NN*BB)/64, 256, 0, stream>>>(x, w, att, outf, natt1, natt2, rsBN);
  k_eatt   <<<MM, 256, 0, stream>>>(elist, eoff, ecnt, nidx, natt2, eatt2);
  k_alpha  <<<NN, 64, 0, stream>>>(nlist, noff, ncnt, eidx, natt1, eatt2, alpha);
  k_edge   <<<MM*4, 256, 0, stream>>>(elist, eoff, ecnt, nidx, outf, alpha, es, ef, nrm);
  k_pair   <<<MM*MM, 64, 0, stream>>>(es, nrm, pairl);
  k_out    <<<NN, 256, 0, stream>>>(nlist, noff, ncnt, eidx, alpha, ef, outf);
  k_lred   <<<256, 256, 0, stream>>>(pairl, rsBN, ncnt, es, ecnt, partial);
  k_lfin   <<<1, 256, 0, stream>>>(partial, outf);
}